// Round 16
// baseline (537.631 us; speedup 1.0000x reference)
//
#include <hip/hip_runtime.h>
#include <hip/hip_cooperative_groups.h>
#include <math.h>

// ---------------------------------------------------------------------------
// HPFNetCovPool round 16 (R15 fixed: compile error in MODE3 placeholder).
//  - conv6b_k: R10 conv schedule, K-split 2->4 (grid 1024 = 3 resident/CU by
//    LDS) for more TLP across barrier drains; combine sums 4 partials.
//  - ns_chain_k: entire NS chain (cov->Z0, Y0, 3 iters, fin) as ONE
//    cooperative kernel with grid.sync() between stages. Stage code + buffer
//    rotation identical to R14 (269us best).
// fmt storage: [batch][kt=k/32][row(256)][128B]; 128B = 8x16B slots,
// slot_log = plane*4 + ((k&31)>>3), stored at slot_log ^ (row&7).
// ---------------------------------------------------------------------------

namespace cg = cooperative_groups;

typedef __attribute__((ext_vector_type(8))) short bf16x8;
typedef __attribute__((ext_vector_type(4))) float f32x4;
typedef __attribute__((ext_vector_type(4))) unsigned u32x4;
typedef __attribute__((ext_vector_type(2))) unsigned u32x2;

__device__ __forceinline__ unsigned fbits(float f) { union { float f; unsigned u; } x; x.f = f; return x.u; }
__device__ __forceinline__ float bitsf(unsigned u) { union { float f; unsigned u; } x; x.u = u; return x.f; }

__device__ __forceinline__ unsigned pack_h(float a, float b) {
  return (fbits(a) >> 16) | (fbits(b) & 0xFFFF0000u);
}
__device__ __forceinline__ unsigned pack_l(float a, float b) {
  float la = a - bitsf(fbits(a) & 0xFFFF0000u);
  float lb = b - bitsf(fbits(b) & 0xFFFF0000u);
  return (fbits(la) >> 16) | (fbits(lb) & 0xFFFF0000u);
}

__device__ __forceinline__ const bf16x8* fragp(const char* M, int kt, int row,
                                               int g, int pl) {
  return (const bf16x8*)(M + (size_t)kt * 32768 + (size_t)row * 128 +
                         ((((pl << 2) + g) ^ (row & 7)) << 4));
}
__device__ __forceinline__ const bf16x8* fragl(const char* L, int kt, int row,
                                               int g, int pl) {
  return (const bf16x8*)(L + kt * 8192 + row * 128 +
                         ((((pl << 2) + g) ^ (row & 7)) << 4));
}

__device__ __forceinline__ void write_quad_g(char* M, int row, int k0,
                                             const float* v) {
  char* rp = M + (size_t)(k0 >> 5) * 32768 + (size_t)row * 128;
  const int s = (k0 & 31) >> 3, bo = (k0 & 7) * 2;
  *(u32x2*)(rp + (((s) ^ (row & 7)) << 4) + bo) =
      (u32x2){pack_h(v[0], v[1]), pack_h(v[2], v[3])};
  *(u32x2*)(rp + (((s + 4) ^ (row & 7)) << 4) + bo) =
      (u32x2){pack_l(v[0], v[1]), pack_l(v[2], v[3])};
}
__device__ __forceinline__ void write_quad_l(char* L, int row, int k0,
                                             const float* v) {
  char* rp = L + (k0 >> 5) * 8192 + row * 128;
  const int s = (k0 & 31) >> 3, bo = (k0 & 7) * 2;
  *(u32x2*)(rp + (((s) ^ (row & 7)) << 4) + bo) =
      (u32x2){pack_h(v[0], v[1]), pack_h(v[2], v[3])};
  *(u32x2*)(rp + (((s + 4) ^ (row & 7)) << 4) + bo) =
      (u32x2){pack_l(v[0], v[1]), pack_l(v[2], v[3])};
}
__device__ __forceinline__ void read_quad_g(const char* M, int row, int k0,
                                            float* v) {
  const char* rp = M + (size_t)(k0 >> 5) * 32768 + (size_t)row * 128;
  const int s = (k0 & 31) >> 3, bo = (k0 & 7) * 2;
  const u32x2 hq = *(const u32x2*)(rp + (((s) ^ (row & 7)) << 4) + bo);
  const u32x2 lq = *(const u32x2*)(rp + (((s + 4) ^ (row & 7)) << 4) + bo);
  v[0] = bitsf(hq[0] << 16) + bitsf(lq[0] << 16);
  v[1] = bitsf(hq[0] & 0xFFFF0000u) + bitsf(lq[0] & 0xFFFF0000u);
  v[2] = bitsf(hq[1] << 16) + bitsf(lq[1] << 16);
  v[3] = bitsf(hq[1] & 0xFFFF0000u) + bitsf(lq[1] & 0xFFFF0000u);
}

#define MFMA3(c, aH, aL, bH, bL)                                            \
  c = __builtin_amdgcn_mfma_f32_16x16x32_bf16(aL, bH, c, 0, 0, 0);          \
  c = __builtin_amdgcn_mfma_f32_16x16x32_bf16(aH, bL, c, 0, 0, 0);          \
  c = __builtin_amdgcn_mfma_f32_16x16x32_bf16(aH, bH, c, 0, 0, 0);

#define LGKM_BAR() do { asm volatile("s_waitcnt lgkmcnt(0)" ::: "memory"); \
                        __builtin_amdgcn_s_barrier(); } while (0)

// ---------------------------------------------------------------------------
// prep: [0,64) w_bn->Wf fmt ; [64,144) build W2 permuted to match MODE3 store.
__global__ __launch_bounds__(256) void prep_k(
    const float* __restrict__ w_bn, const float* __restrict__ w_type,
    const float* __restrict__ w_flag, char* __restrict__ Wf,
    float* __restrict__ W2)
{
  const int bid = blockIdx.x;
  if (bid < 64) {
    const int kt = bid, r = threadIdx.x;
    const float* src = w_bn + (size_t)r * 2048 + kt * 32;
    char* rp = Wf + (size_t)kt * 32768 + (size_t)r * 128;
#pragma unroll
    for (int s = 0; s < 4; ++s) {
      float x[8];
#pragma unroll
      for (int e = 0; e < 8; ++e) x[e] = src[s * 8 + e];
      *(u32x4*)(rp + ((s ^ (r & 7)) << 4)) =
          (u32x4){pack_h(x[0], x[1]), pack_h(x[2], x[3]),
                  pack_h(x[4], x[5]), pack_h(x[6], x[7])};
      *(u32x4*)(rp + (((s + 4) ^ (r & 7)) << 4)) =
          (u32x4){pack_l(x[0], x[1]), pack_l(x[2], x[3]),
                  pack_l(x[4], x[5]), pack_l(x[6], x[7])};
    }
  } else {
    const int idx = bid - 64;          // [0,80)
    const int v = idx >> 4, chunk = idx & 15;
    const float* src = (v < 4) ? (w_type + (size_t)v * 32896) : w_flag;
    const int s0 = chunk * 4096 + threadIdx.x * 16;
    float outv[16];
#pragma unroll
    for (int q = 0; q < 16; ++q) {
      const int s = s0 + q;
      const int jbp = s >> 14, r = s & 16383;
      const int ttid = r >> 5, qq = r & 31;
      const int m = qq >> 4, n = (qq >> 2) & 3, jj = qq & 3;
      const int ww = ttid >> 6, ll = ttid & 63;
      const int i = ww * 32 + m * 16 + (ll >> 4) * 4 + jj;
      const int jcol = jbp * 64 + n * 16 + (ll & 15);
      const int rr = i < jcol ? i : jcol, cc = i < jcol ? jcol : i;
      const int t = rr * 256 - (rr * (rr - 1)) / 2 + (cc - rr);
      outv[q] = src[t] * (i == jcol ? 1.0f : 0.5f);
    }
    float* dst = W2 + (size_t)v * 65536 + s0;
#pragma unroll
    for (int q = 0; q < 4; ++q)
      *(f32x4*)(dst + q * 4) = *(f32x4*)(outv + q * 4);
  }
}

// ---------------------------------------------------------------------------
// conv6b: partial X = Wf[kt quarter] @ F^T, fused transpose.
// grid (4 jb, 64 bz, 4 ks), 512 thr. 16 ksteps = 4 phase-pairs.
__global__ __launch_bounds__(512) void conv6b_k(
    const char* __restrict__ Wf, const float* __restrict__ F,
    float* __restrict__ Xpart)
{
  __shared__ float bf32s[2][64 * 33];
  __shared__ __align__(16) char bfmt[2][2][8192];

  const int tid = threadIdx.x, lane = tid & 63, w = tid >> 6;
  const int wr = w >> 1, wc = w & 1, fr = lane & 15, g = lane >> 4;
  const int jb = blockIdx.x * 64, bz = blockIdx.y, ks = blockIdx.z;
  const int kb = ks * 16;
  const float* Fb = F + (size_t)bz * 524288;

  const int blc = tid >> 4, blpx = (tid & 15) * 4;
  const int pkpx = tid >> 3, pkq = tid & 3, pkpl = (tid >> 2) & 1;

  f32x4 acc[4][2] = {};
  bf16x8 paA[4][2], paB[4][2];

  auto bload = [&](int t) -> float4 {
    return *(const float4*)(Fb + ((size_t)(kb + t) * 32 + blc) * 256 + jb + blpx);
  };
  auto bf32w = [&](int kk, const float4& r) {
    float* p = &bf32s[kk][0];
    p[(blpx + 0) * 33 + blc] = r.x;
    p[(blpx + 1) * 33 + blc] = r.y;
    p[(blpx + 2) * 33 + blc] = r.z;
    p[(blpx + 3) * 33 + blc] = r.w;
  };
  auto aload = [&](int t, bf16x8 (*pa)[2]) {
#pragma unroll
    for (int m = 0; m < 4; ++m) {
      const int r = wr * 64 + m * 16 + fr;
#pragma unroll
      for (int pl = 0; pl < 2; ++pl) pa[m][pl] = *fragp(Wf, kb + t, r, g, pl);
    }
  };
  auto pack = [&](int kk, int dq) {
    const float* p = &bf32s[kk][pkpx * 33 + pkq * 8];
    float x[8];
#pragma unroll
    for (int e = 0; e < 8; ++e) x[e] = p[e];
    u32x4 outv;
    if (pkpl == 0)
      outv = (u32x4){pack_h(x[0], x[1]), pack_h(x[2], x[3]),
                     pack_h(x[4], x[5]), pack_h(x[6], x[7])};
    else
      outv = (u32x4){pack_l(x[0], x[1]), pack_l(x[2], x[3]),
                     pack_l(x[4], x[5]), pack_l(x[6], x[7])};
    const int slot = ((pkpl << 2) + pkq) ^ (pkpx & 7);
    *(u32x4*)(&bfmt[dq][kk][pkpx * 128 + slot * 16]) = outv;
  };
  auto gemmstep = [&](int sq, int kk, bf16x8 (*pa)[2]) {
    bf16x8 bH[2], bL[2];
#pragma unroll
    for (int n = 0; n < 2; ++n) {
      const int r = wc * 32 + n * 16 + fr;
      const char* rp = &bfmt[sq][kk][r * 128];
      bH[n] = *(const bf16x8*)(rp + ((g ^ (r & 7)) << 4));
      bL[n] = *(const bf16x8*)(rp + (((g + 4) ^ (r & 7)) << 4));
    }
#pragma unroll
    for (int m = 0; m < 4; ++m)
#pragma unroll
      for (int n = 0; n < 2; ++n) {
        f32x4 c = acc[m][n];
        MFMA3(c, pa[m][0], pa[m][1], bH[n], bL[n]);
        acc[m][n] = c;
      }
  };

  float4 b0 = bload(0), b1 = bload(1), b2 = bload(2), b3 = bload(3);
  float4 blE0 = bload(4), blE1 = bload(5);
  float4 blO0 = bload(6), blO1 = bload(7);
  aload(0, paA);
  aload(1, paB);

  bf32w(0, b0); bf32w(1, b1);
  LGKM_BAR();
  pack(0, 0); pack(1, 0);
  LGKM_BAR();
  bf32w(0, b2); bf32w(1, b3);
  LGKM_BAR();

  for (int pp = 0; pp < 4; ++pp) {
    const int k4 = 4 * pp;
    gemmstep(0, 0, paA);
    gemmstep(0, 1, paB);
    aload(k4 + 2, paA);
    aload(k4 + 3, paB);
    pack(0, 1); pack(1, 1);
    LGKM_BAR();
    if (pp < 3) { bf32w(0, blE0); bf32w(1, blE1); }
    if (pp < 2) { blE0 = bload(k4 + 8); blE1 = bload(k4 + 9); }
    LGKM_BAR();
    gemmstep(1, 0, paA);
    gemmstep(1, 1, paB);
    if (pp < 3) { aload(k4 + 4, paA); aload(k4 + 5, paB); }
    if (pp < 3) { pack(0, 0); pack(1, 0); }
    LGKM_BAR();
    if (pp < 3) { bf32w(0, blO0); bf32w(1, blO1); }
    if (pp < 2) { blO0 = bload(k4 + 10); blO1 = bload(k4 + 11); }
    LGKM_BAR();
  }

  float* Xp = Xpart + ((size_t)ks * 64 + bz) * 65536;
#pragma unroll
  for (int m = 0; m < 4; ++m) {
    const int gi0 = wr * 64 + m * 16 + g * 4;
#pragma unroll
    for (int n = 0; n < 2; ++n) {
      const int gj = jb + wc * 32 + n * 16 + fr;
#pragma unroll
      for (int j = 0; j < 4; ++j)
        Xp[(size_t)(gi0 + j) * 256 + gj] = acc[m][n][j];
    }
  }
}

// ---------------------------------------------------------------------------
// combine: X = sum of 4 partials + bias -> fmt; mu; trace partials.
__global__ __launch_bounds__(256) void combine_k(
    const float* __restrict__ Xp, const float* __restrict__ bias,
    char* __restrict__ X, float* __restrict__ mu, float* __restrict__ nrm_part)
{
  const int chunk = blockIdx.x, bz = blockIdx.y;
  const int tid = threadIdx.x, lane = tid & 63, w = tid >> 6;
  const float* p0 = Xp + (size_t)bz * 65536;
  char* Xb = X + (size_t)bz * 262144;
  float tracc = 0.f;
#pragma unroll
  for (int i = 0; i < 8; ++i) {
    const int r = chunk * 32 + w * 8 + i;
    const size_t off = (size_t)r * 256 + lane * 4;
    const float4 a = *(const float4*)(p0 + off);
    const float4 b = *(const float4*)(p0 + 64ull * 65536 + off);
    const float4 c = *(const float4*)(p0 + 128ull * 65536 + off);
    const float4 d = *(const float4*)(p0 + 192ull * 65536 + off);
    const float bi = bias[r];
    float v[4] = {a.x + b.x + c.x + d.x + bi, a.y + b.y + c.y + d.y + bi,
                  a.z + b.z + c.z + d.z + bi, a.w + b.w + c.w + d.w + bi};
    float s = v[0] + v[1] + v[2] + v[3];
    float ss = v[0] * v[0] + v[1] * v[1] + v[2] * v[2] + v[3] * v[3];
#pragma unroll
    for (int o = 32; o > 0; o >>= 1) {
      s += __shfl_down(s, o);
      ss += __shfl_down(ss, o);
    }
    const float st = __shfl(s, 0), sst = __shfl(ss, 0);
    const float m = st * (1.f / 256.f);
    if (lane == 0) mu[bz * 256 + r] = m;
    tracc += sst * (1.f / 256.f) - m * m;
    write_quad_g(Xb, r, lane * 4, v);
  }
  __shared__ float red[4];
  if (lane == 0) red[w] = tracc;
  __syncthreads();
  if (tid == 0)
    nrm_part[bz * 8 + chunk] = red[0] + red[1] + red[2] + red[3];
}

__device__ __forceinline__ float nrm_sum(const float* nrmp, int bz) {
  float nv = 0.f;
#pragma unroll
  for (int q = 0; q < 8; ++q) nv += nrmp[bz * 8 + q];
  return nv;
}

// ---------------------------------------------------------------------------
// Shared stage-1: acc[2][4] = A @ B[:,panel]^T over K=256.
__device__ __forceinline__ void stage1_gemm(
    const char* Ab, const char* Bb, int jb, int w, int fr, int g,
    f32x4 (&acc)[2][4])
{
  bf16x8 pa[2][2][2], pb[2][4][2];
#pragma unroll
  for (int par = 0; par < 2; ++par) {
#pragma unroll
    for (int m = 0; m < 2; ++m) {
      const int r = w * 32 + m * 16 + fr;
#pragma unroll
      for (int pl = 0; pl < 2; ++pl) pa[par][m][pl] = *fragp(Ab, par, r, g, pl);
    }
#pragma unroll
    for (int n = 0; n < 4; ++n) {
      const int r = jb + n * 16 + fr;
#pragma unroll
      for (int pl = 0; pl < 2; ++pl) pb[par][n][pl] = *fragp(Bb, par, r, g, pl);
    }
  }
  for (int t2 = 0; t2 < 8; t2 += 2) {
#pragma unroll
    for (int par = 0; par < 2; ++par) {
      const int t = t2 + par;
      bf16x8 aH[2], aL[2], bH[4], bL[4];
#pragma unroll
      for (int m = 0; m < 2; ++m) { aH[m] = pa[par][m][0]; aL[m] = pa[par][m][1]; }
#pragma unroll
      for (int n = 0; n < 4; ++n) { bH[n] = pb[par][n][0]; bL[n] = pb[par][n][1]; }
      if (t + 2 < 8) {
#pragma unroll
        for (int m = 0; m < 2; ++m) {
          const int r = w * 32 + m * 16 + fr;
#pragma unroll
          for (int pl = 0; pl < 2; ++pl)
            pa[par][m][pl] = *fragp(Ab, t + 2, r, g, pl);
        }
#pragma unroll
        for (int n = 0; n < 4; ++n) {
          const int r = jb + n * 16 + fr;
#pragma unroll
          for (int pl = 0; pl < 2; ++pl)
            pb[par][n][pl] = *fragp(Bb, t + 2, r, g, pl);
        }
      }
#pragma unroll
      for (int m = 0; m < 2; ++m)
#pragma unroll
        for (int n = 0; n < 4; ++n) {
          f32x4 c = acc[m][n];
          MFMA3(c, aH[m], aL[m], bH[n], bL[n]);
          acc[m][n] = c;
        }
    }
  }
}

// ---------------------------------------------------------------------------
// NS chain stages as device functions (MODE 0/1/2 generic; FIN separate).
// MODE 0 COV : Z0 = 1.5I - 0.5*(cov/nrm) -> outB
// MODE 1 Y0  : Y0 = 3*Z0 - 2*Z0^2 -> outA   (Bsrc = Z0)
// MODE 2 IT  : Yn (outA), Zn (outB)
template <int MODE>
__device__ void col_stage(
    const char* A1, const char* Bsrc, const char* Ys, const char* Zs,
    char* outA, char* outB, const float* mu, const float* nrmp,
    char* Plds, int blk, int tid)
{
  static_assert(MODE >= 0 && MODE <= 2, "FIN handled by col_stage_fin");
  const int lane = tid & 63, w = tid >> 6;
  const int fr = lane & 15, g = lane >> 4;
  const int bz = (blk & 7) * 8 + ((blk >> 3) & 7);  // XCD batch affinity
  const int jbp = blk >> 6;                          // col panel [0,4)
  const int jb = jbp * 64;
  const size_t MB = 262144;
  const char* Ab = A1 + (size_t)bz * MB;
  const char* Bb = Bsrc + (size_t)bz * MB;
  const int r0 = g * 4;

  f32x4 acc[2][4] = {};
  stage1_gemm(Ab, Bb, jb, w, fr, g, acc);

  if constexpr (MODE == 0) {
    const float rn = 1.0f / nrm_sum(nrmp, bz);
    const float* mub = mu + bz * 256;
    char* oB = outB + (size_t)bz * MB;
#pragma unroll
    for (int m = 0; m < 2; ++m) {
      const int gi0 = w * 32 + m * 16 + r0;
#pragma unroll
      for (int n = 0; n < 4; ++n) {
        const int gj = jb + n * 16 + fr;
        float zz[4];
#pragma unroll
        for (int j = 0; j < 4; ++j) {
          const float v =
              (acc[m][n][j] * (1.f / 256.f) - mub[gi0 + j] * mub[gj]) * rn;
          zz[j] = (gi0 + j == gj ? 1.5f : 0.f) - 0.5f * v;
        }
        write_quad_g(oB, gj, gi0, zz);
      }
    }
  } else if constexpr (MODE == 1) {
    char* oA = outA + (size_t)bz * MB;
#pragma unroll
    for (int m = 0; m < 2; ++m) {
      const int gi0 = w * 32 + m * 16 + r0;
#pragma unroll
      for (int n = 0; n < 4; ++n) {
        const int gj = jb + n * 16 + fr;
        float zv[4], vv[4];
        read_quad_g(Bb, gj, gi0, zv);
#pragma unroll
        for (int j = 0; j < 4; ++j) vv[j] = 3.f * zv[j] - 2.f * acc[m][n][j];
        write_quad_g(oA, gj, gi0, vv);
      }
    }
  } else {  // MODE == 2
#pragma unroll
    for (int m = 0; m < 2; ++m) {
      const int gi0 = w * 32 + m * 16 + r0;
#pragma unroll
      for (int n = 0; n < 4; ++n) {
        const int jl = n * 16 + fr;
        float vv[4] = {acc[m][n][0], acc[m][n][1], acc[m][n][2], acc[m][n][3]};
        write_quad_l(Plds, jl, gi0, vv);
      }
    }
    const char* Yb = Ys + (size_t)bz * MB;
    const char* Zb = Zs + (size_t)bz * MB;
    bf16x8 py[2][2][2], pz[2][2][2];
#pragma unroll
    for (int par = 0; par < 2; ++par)
#pragma unroll
      for (int m = 0; m < 2; ++m) {
        const int r = w * 32 + m * 16 + fr;
#pragma unroll
        for (int pl = 0; pl < 2; ++pl) {
          py[par][m][pl] = *fragp(Yb, par, r, g, pl);
          pz[par][m][pl] = *fragp(Zb, par, r, g, pl);
        }
      }
    __syncthreads();

    f32x4 aY[2][4] = {}, aZ[2][4] = {};
    for (int t2 = 0; t2 < 8; t2 += 2) {
#pragma unroll
      for (int par = 0; par < 2; ++par) {
        const int t = t2 + par;
        bf16x8 yH[2], yL[2], zH[2], zL[2];
#pragma unroll
        for (int m = 0; m < 2; ++m) {
          yH[m] = py[par][m][0]; yL[m] = py[par][m][1];
          zH[m] = pz[par][m][0]; zL[m] = pz[par][m][1];
        }
        if (t + 2 < 8) {
#pragma unroll
          for (int m = 0; m < 2; ++m) {
            const int r = w * 32 + m * 16 + fr;
#pragma unroll
            for (int pl = 0; pl < 2; ++pl) {
              py[par][m][pl] = *fragp(Yb, t + 2, r, g, pl);
              pz[par][m][pl] = *fragp(Zb, t + 2, r, g, pl);
            }
          }
        }
        bf16x8 bH[4], bL[4];
#pragma unroll
        for (int n = 0; n < 4; ++n) {
          const int jl = n * 16 + fr;
          bH[n] = *fragl(Plds, t, jl, g, 0);
          bL[n] = *fragl(Plds, t, jl, g, 1);
        }
#pragma unroll
        for (int m = 0; m < 2; ++m)
#pragma unroll
          for (int n = 0; n < 4; ++n) {
            f32x4 cy = aY[m][n];
            MFMA3(cy, yH[m], yL[m], bH[n], bL[n]);
            aY[m][n] = cy;
            f32x4 cz = aZ[m][n];
            MFMA3(cz, zH[m], zL[m], bH[n], bL[n]);
            aZ[m][n] = cz;
          }
      }
    }
    char* oA = outA + (size_t)bz * MB;
    char* oB = outB + (size_t)bz * MB;
#pragma unroll
    for (int m = 0; m < 2; ++m) {
      const int gi0 = w * 32 + m * 16 + r0;
#pragma unroll
      for (int n = 0; n < 4; ++n) {
        const int gj = jb + n * 16 + fr;
        float base[4], vv[4];
        read_quad_g(Yb, gj, gi0, base);
#pragma unroll
        for (int j = 0; j < 4; ++j) vv[j] = 1.5f * base[j] - 0.5f * aY[m][n][j];
        write_quad_g(oA, gj, gi0, vv);
        read_quad_g(Zb, gj, gi0, base);
#pragma unroll
        for (int j = 0; j < 4; ++j) vv[j] = 1.5f * base[j] - 0.5f * aZ[m][n][j];
        write_quad_g(oB, gj, gi0, vv);
      }
    }
  }
}

// FIN: S = (1.5Y - 0.5 Y@P) * sqrt(nrm) -> Sf permuted-linear. A1=Z, Ys=Y.
__device__ void col_stage_fin(
    const char* A1, const char* Ys, const float* nrmp, float* Sf,
    char* Plds, int blk, int tid)
{
  const int lane = tid & 63, w = tid >> 6;
  const int fr = lane & 15, g = lane >> 4;
  const int bz = (blk & 7) * 8 + ((blk >> 3) & 7);
  const int jbp = blk >> 6;
  const int jb = jbp * 64;
  const size_t MB = 262144;
  const char* Ab = A1 + (size_t)bz * MB;
  const char* Bb = Ys + (size_t)bz * MB;
  const int r0 = g * 4;

  f32x4 acc[2][4] = {};
  stage1_gemm(Ab, Bb, jb, w, fr, g, acc);

#pragma unroll
  for (int m = 0; m < 2; ++m) {
    const int gi0 = w * 32 + m * 16 + r0;
#pragma unroll
    for (int n = 0; n < 4; ++n) {
      const int jl = n * 16 + fr;
      float vv[4] = {acc[m][n][0], acc[m][n][1], acc[m][n][2], acc[m][n][3]};
      write_quad_l(Plds, jl, gi0, vv);
    }
  }
  const char* Yb = Bb;
  bf16x8 py[2][2][2];
#pragma unroll
  for (int par = 0; par < 2; ++par)
#pragma unroll
    for (int m = 0; m < 2; ++m) {
      const int r = w * 32 + m * 16 + fr;
#pragma unroll
      for (int pl = 0; pl < 2; ++pl) py[par][m][pl] = *fragp(Yb, par, r, g, pl);
    }
  __syncthreads();

  f32x4 aY[2][4] = {};
  for (int t2 = 0; t2 < 8; t2 += 2) {
#pragma unroll
    for (int par = 0; par < 2; ++par) {
      const int t = t2 + par;
      bf16x8 yH[2], yL[2];
#pragma unroll
      for (int m = 0; m < 2; ++m) { yH[m] = py[par][m][0]; yL[m] = py[par][m][1]; }
      if (t + 2 < 8) {
#pragma unroll
        for (int m = 0; m < 2; ++m) {
          const int r = w * 32 + m * 16 + fr;
#pragma unroll
          for (int pl = 0; pl < 2; ++pl) py[par][m][pl] = *fragp(Yb, t + 2, r, g, pl);
        }
      }
      bf16x8 bH[4], bL[4];
#pragma unroll
      for (int n = 0; n < 4; ++n) {
        const int jl = n * 16 + fr;
        bH[n] = *fragl(Plds, t, jl, g, 0);
        bL[n] = *fragl(Plds, t, jl, g, 1);
      }
#pragma unroll
      for (int m = 0; m < 2; ++m)
#pragma unroll
        for (int n = 0; n < 4; ++n) {
          f32x4 cy = aY[m][n];
          MFMA3(cy, yH[m], yL[m], bH[n], bL[n]);
          aY[m][n] = cy;
        }
    }
  }
  const float sq = sqrtf(nrm_sum(nrmp, bz));
  float* Sb = Sf + (size_t)bz * 65536 + (size_t)jbp * 16384 + (size_t)tid * 32;
#pragma unroll
  for (int m = 0; m < 2; ++m) {
    const int gi0 = w * 32 + m * 16 + r0;
#pragma unroll
    for (int n = 0; n < 4; ++n) {
      const int gj = jb + n * 16 + fr;
      float base[4];
      read_quad_g(Yb, gj, gi0, base);
      f32x4 vv;
#pragma unroll
      for (int j = 0; j < 4; ++j)
        vv[j] = (1.5f * base[j] - 0.5f * aY[m][n][j]) * sq;
      *(f32x4*)(Sb + m * 16 + n * 4) = vv;
    }
  }
}

// ---------------------------------------------------------------------------
// Cooperative NS chain: all 6 stages with grid.sync() between (R14 rotation).
__global__ __launch_bounds__(512) void ns_chain_k(
    char* P0, char* P1, char* P2, char* P3,
    const float* mu, const float* nrmp, float* Sf)
{
  __shared__ __align__(16) char Plds[65536];
  cg::grid_group grid = cg::this_grid();
  const int blk = blockIdx.x, tid = threadIdx.x;

  // cov: Z0 -> P2   (X = P0)
  col_stage<0>(P0, P0, nullptr, nullptr, nullptr, P2, mu, nrmp, Plds, blk, tid);
  grid.sync();
  // Y0 = 3*Z0 - 2*Z0^2 -> P3
  col_stage<1>(P2, P2, nullptr, nullptr, P3, nullptr, mu, nrmp, Plds, blk, tid);
  grid.sync();
  // it1: Z=P2, Y=P3 -> Yn P0, Zn P1
  col_stage<2>(P2, P3, P3, P2, P0, P1, mu, nrmp, Plds, blk, tid);
  grid.sync();
  // it2: Z=P1, Y=P0 -> Yn P3, Zn P2
  col_stage<2>(P1, P0, P0, P1, P3, P2, mu, nrmp, Plds, blk, tid);
  grid.sync();
  // it3: Z=P2, Y=P3 -> Yn P1, Zn P0
  col_stage<2>(P2, P3, P3, P2, P1, P0, mu, nrmp, Plds, blk, tid);
  grid.sync();
  // fin: Z=P0, Y=P1 -> Sf
  col_stage_fin(P0, P1, nrmp, Sf, Plds, blk, tid);
}

// ---------------------------------------------------------------------------
// Heads: out[b,v] = dot(S_b, W2_v) + bias (identical permuted layouts).
__global__ __launch_bounds__(256) void head2(
    const float* __restrict__ Sf, const float* __restrict__ W2,
    const float* __restrict__ b_type, const float* __restrict__ b_flag,
    float* __restrict__ out)
{
  const int b = blockIdx.x, v = blockIdx.y, tid = threadIdx.x;
  const float4* s4 = (const float4*)(Sf + (size_t)b * 65536);
  const float4* w4 = (const float4*)(W2 + (size_t)v * 65536);
  float acc = 0.f;
  for (int i = tid; i < 16384; i += 256) {
    const float4 a = s4[i], c = w4[i];
    acc += a.x * c.x + a.y * c.y + a.z * c.z + a.w * c.w;
  }
  __shared__ float red[256];
  red[tid] = acc;
  __syncthreads();
  for (int o = 128; o > 0; o >>= 1) {
    if (tid < o) red[tid] += red[tid + o];
    __syncthreads();
  }
  if (tid == 0) {
    if (v < 4) out[b * 4 + v] = red[0] + b_type[v];
    else       out[256 + b] = red[0] + b_flag[0];
  }
}

// ---------------------------------------------------------------------------
extern "C" void kernel_launch(void* const* d_in, const int* in_sizes, int n_in,
                              void* d_out, int out_size, void* d_ws, size_t ws_size,
                              hipStream_t stream)
{
  const float* features = (const float*)d_in[0];
  const float* w_bn     = (const float*)d_in[1];
  const float* b_bn     = (const float*)d_in[2];
  const float* w_type   = (const float*)d_in[3];
  const float* b_type   = (const float*)d_in[4];
  const float* w_flag   = (const float*)d_in[5];
  const float* b_flag   = (const float*)d_in[6];
  float* out = (float*)d_out;

  char* W = (char*)d_ws;
  const size_t PB = 16777216;
  char* P0 = W;           char* P1 = W + PB;     char* P2 = W + 2 * PB;
  char* P3 = W + 3 * PB;  char* P4 = W + 4 * PB;
  char* Wf = W + 5 * PB;                          // 2 MB
  float* W2 = (float*)(W + 5 * PB + 2097152);     // 1.31 MB
  float* mu = (float*)(W + 5 * PB + 4194304);     // 64 KB
  float* nrm_part = mu + 16384;                   // 512 floats
  float* Xpart = (float*)(W + 5 * PB + 8388608);  // 4 x 16.78 MB
  float* Sf = (float*)P4;                         // final S fp32 (P4 free)

  prep_k<<<dim3(144), dim3(256), 0, stream>>>(w_bn, w_type, w_flag, Wf, W2);
  conv6b_k<<<dim3(4, 64, 4), dim3(512), 0, stream>>>(Wf, features, Xpart);
  combine_k<<<dim3(8, 64), dim3(256), 0, stream>>>(Xpart, b_bn, P0, mu, nrm_part);

  {
    char* p0 = P0; char* p1 = P1; char* p2 = P2; char* p3 = P3;
    const float* mu_ = mu; const float* nr_ = nrm_part; float* sf_ = Sf;
    void* kargs[] = {&p0, &p1, &p2, &p3, (void*)&mu_, (void*)&nr_, &sf_};
    (void)hipLaunchCooperativeKernel((void*)ns_chain_k, dim3(256), dim3(512),
                                     kargs, 0, stream);
  }

  head2<<<dim3(64, 5), dim3(256), 0, stream>>>(Sf, W2, b_type, b_flag, out);
  (void)in_sizes; (void)n_in; (void)out_size; (void)ws_size;
}

// Round 17
// 289.893 us; speedup vs baseline: 1.8546x; 1.8546x over previous
//
#include <hip/hip_runtime.h>
#include <math.h>

// ---------------------------------------------------------------------------
// HPFNetCovPool round 17 = R14 (best, 269us) + ISOLATED conv change:
// conv K-split 2->4 (grid 1024 = 3 resident blocks/CU by LDS) for more TLP
// across per-kstep barrier drains; combine sums 4 partials.
// NS chain: R14's 6 separate col_k dispatches (cooperative fusion REVERTED --
// R16 showed grid.sync costs ~40us each + L2 invalidation on MI355X).
// fmt storage: [batch][kt=k/32][row(256)][128B]; 128B = 8x16B slots,
// slot_log = plane*4 + ((k&31)>>3), stored at slot_log ^ (row&7).
// ---------------------------------------------------------------------------

typedef __attribute__((ext_vector_type(8))) short bf16x8;
typedef __attribute__((ext_vector_type(4))) float f32x4;
typedef __attribute__((ext_vector_type(4))) unsigned u32x4;
typedef __attribute__((ext_vector_type(2))) unsigned u32x2;

__device__ __forceinline__ unsigned fbits(float f) { union { float f; unsigned u; } x; x.f = f; return x.u; }
__device__ __forceinline__ float bitsf(unsigned u) { union { float f; unsigned u; } x; x.u = u; return x.f; }

__device__ __forceinline__ unsigned pack_h(float a, float b) {
  return (fbits(a) >> 16) | (fbits(b) & 0xFFFF0000u);
}
__device__ __forceinline__ unsigned pack_l(float a, float b) {
  float la = a - bitsf(fbits(a) & 0xFFFF0000u);
  float lb = b - bitsf(fbits(b) & 0xFFFF0000u);
  return (fbits(la) >> 16) | (fbits(lb) & 0xFFFF0000u);
}

__device__ __forceinline__ const bf16x8* fragp(const char* M, int kt, int row,
                                               int g, int pl) {
  return (const bf16x8*)(M + (size_t)kt * 32768 + (size_t)row * 128 +
                         ((((pl << 2) + g) ^ (row & 7)) << 4));
}
__device__ __forceinline__ const bf16x8* fragl(const char* L, int kt, int row,
                                               int g, int pl) {
  return (const bf16x8*)(L + kt * 8192 + row * 128 +
                         ((((pl << 2) + g) ^ (row & 7)) << 4));
}

__device__ __forceinline__ void write_quad_g(char* M, int row, int k0,
                                             const float* v) {
  char* rp = M + (size_t)(k0 >> 5) * 32768 + (size_t)row * 128;
  const int s = (k0 & 31) >> 3, bo = (k0 & 7) * 2;
  *(u32x2*)(rp + (((s) ^ (row & 7)) << 4) + bo) =
      (u32x2){pack_h(v[0], v[1]), pack_h(v[2], v[3])};
  *(u32x2*)(rp + (((s + 4) ^ (row & 7)) << 4) + bo) =
      (u32x2){pack_l(v[0], v[1]), pack_l(v[2], v[3])};
}
__device__ __forceinline__ void write_quad_l(char* L, int row, int k0,
                                             const float* v) {
  char* rp = L + (k0 >> 5) * 8192 + row * 128;
  const int s = (k0 & 31) >> 3, bo = (k0 & 7) * 2;
  *(u32x2*)(rp + (((s) ^ (row & 7)) << 4) + bo) =
      (u32x2){pack_h(v[0], v[1]), pack_h(v[2], v[3])};
  *(u32x2*)(rp + (((s + 4) ^ (row & 7)) << 4) + bo) =
      (u32x2){pack_l(v[0], v[1]), pack_l(v[2], v[3])};
}
__device__ __forceinline__ void read_quad_g(const char* M, int row, int k0,
                                            float* v) {
  const char* rp = M + (size_t)(k0 >> 5) * 32768 + (size_t)row * 128;
  const int s = (k0 & 31) >> 3, bo = (k0 & 7) * 2;
  const u32x2 hq = *(const u32x2*)(rp + (((s) ^ (row & 7)) << 4) + bo);
  const u32x2 lq = *(const u32x2*)(rp + (((s + 4) ^ (row & 7)) << 4) + bo);
  v[0] = bitsf(hq[0] << 16) + bitsf(lq[0] << 16);
  v[1] = bitsf(hq[0] & 0xFFFF0000u) + bitsf(lq[0] & 0xFFFF0000u);
  v[2] = bitsf(hq[1] << 16) + bitsf(lq[1] << 16);
  v[3] = bitsf(hq[1] & 0xFFFF0000u) + bitsf(lq[1] & 0xFFFF0000u);
}

#define MFMA3(c, aH, aL, bH, bL)                                            \
  c = __builtin_amdgcn_mfma_f32_16x16x32_bf16(aL, bH, c, 0, 0, 0);          \
  c = __builtin_amdgcn_mfma_f32_16x16x32_bf16(aH, bL, c, 0, 0, 0);          \
  c = __builtin_amdgcn_mfma_f32_16x16x32_bf16(aH, bH, c, 0, 0, 0);

#define LGKM_BAR() do { asm volatile("s_waitcnt lgkmcnt(0)" ::: "memory"); \
                        __builtin_amdgcn_s_barrier(); } while (0)

// ---------------------------------------------------------------------------
// prep: [0,64) w_bn->Wf fmt ; [64,144) build W2 permuted to match MODE3 store.
__global__ __launch_bounds__(256) void prep_k(
    const float* __restrict__ w_bn, const float* __restrict__ w_type,
    const float* __restrict__ w_flag, char* __restrict__ Wf,
    float* __restrict__ W2)
{
  const int bid = blockIdx.x;
  if (bid < 64) {
    const int kt = bid, r = threadIdx.x;
    const float* src = w_bn + (size_t)r * 2048 + kt * 32;
    char* rp = Wf + (size_t)kt * 32768 + (size_t)r * 128;
#pragma unroll
    for (int s = 0; s < 4; ++s) {
      float x[8];
#pragma unroll
      for (int e = 0; e < 8; ++e) x[e] = src[s * 8 + e];
      *(u32x4*)(rp + ((s ^ (r & 7)) << 4)) =
          (u32x4){pack_h(x[0], x[1]), pack_h(x[2], x[3]),
                  pack_h(x[4], x[5]), pack_h(x[6], x[7])};
      *(u32x4*)(rp + (((s + 4) ^ (r & 7)) << 4)) =
          (u32x4){pack_l(x[0], x[1]), pack_l(x[2], x[3]),
                  pack_l(x[4], x[5]), pack_l(x[6], x[7])};
    }
  } else {
    const int idx = bid - 64;          // [0,80)
    const int v = idx >> 4, chunk = idx & 15;
    const float* src = (v < 4) ? (w_type + (size_t)v * 32896) : w_flag;
    const int s0 = chunk * 4096 + threadIdx.x * 16;
    float outv[16];
#pragma unroll
    for (int q = 0; q < 16; ++q) {
      const int s = s0 + q;
      const int jbp = s >> 14, r = s & 16383;
      const int ttid = r >> 5, qq = r & 31;
      const int m = qq >> 4, n = (qq >> 2) & 3, jj = qq & 3;
      const int ww = ttid >> 6, ll = ttid & 63;
      const int i = ww * 32 + m * 16 + (ll >> 4) * 4 + jj;
      const int jcol = jbp * 64 + n * 16 + (ll & 15);
      const int rr = i < jcol ? i : jcol, cc = i < jcol ? jcol : i;
      const int t = rr * 256 - (rr * (rr - 1)) / 2 + (cc - rr);
      outv[q] = src[t] * (i == jcol ? 1.0f : 0.5f);
    }
    float* dst = W2 + (size_t)v * 65536 + s0;
#pragma unroll
    for (int q = 0; q < 4; ++q)
      *(f32x4*)(dst + q * 4) = *(f32x4*)(outv + q * 4);
  }
}

// ---------------------------------------------------------------------------
// conv6b: partial X = Wf[kt quarter] @ F^T, fused transpose.
// grid (4 jb, 64 bz, 4 ks), 512 thr. 16 ksteps = 4 phase-pairs.
__global__ __launch_bounds__(512) void conv6b_k(
    const char* __restrict__ Wf, const float* __restrict__ F,
    float* __restrict__ Xpart)
{
  __shared__ float bf32s[2][64 * 33];
  __shared__ __align__(16) char bfmt[2][2][8192];

  const int tid = threadIdx.x, lane = tid & 63, w = tid >> 6;
  const int wr = w >> 1, wc = w & 1, fr = lane & 15, g = lane >> 4;
  const int jb = blockIdx.x * 64, bz = blockIdx.y, ks = blockIdx.z;
  const int kb = ks * 16;
  const float* Fb = F + (size_t)bz * 524288;

  const int blc = tid >> 4, blpx = (tid & 15) * 4;
  const int pkpx = tid >> 3, pkq = tid & 3, pkpl = (tid >> 2) & 1;

  f32x4 acc[4][2] = {};
  bf16x8 paA[4][2], paB[4][2];

  auto bload = [&](int t) -> float4 {
    return *(const float4*)(Fb + ((size_t)(kb + t) * 32 + blc) * 256 + jb + blpx);
  };
  auto bf32w = [&](int kk, const float4& r) {
    float* p = &bf32s[kk][0];
    p[(blpx + 0) * 33 + blc] = r.x;
    p[(blpx + 1) * 33 + blc] = r.y;
    p[(blpx + 2) * 33 + blc] = r.z;
    p[(blpx + 3) * 33 + blc] = r.w;
  };
  auto aload = [&](int t, bf16x8 (*pa)[2]) {
#pragma unroll
    for (int m = 0; m < 4; ++m) {
      const int r = wr * 64 + m * 16 + fr;
#pragma unroll
      for (int pl = 0; pl < 2; ++pl) pa[m][pl] = *fragp(Wf, kb + t, r, g, pl);
    }
  };
  auto pack = [&](int kk, int dq) {
    const float* p = &bf32s[kk][pkpx * 33 + pkq * 8];
    float x[8];
#pragma unroll
    for (int e = 0; e < 8; ++e) x[e] = p[e];
    u32x4 outv;
    if (pkpl == 0)
      outv = (u32x4){pack_h(x[0], x[1]), pack_h(x[2], x[3]),
                     pack_h(x[4], x[5]), pack_h(x[6], x[7])};
    else
      outv = (u32x4){pack_l(x[0], x[1]), pack_l(x[2], x[3]),
                     pack_l(x[4], x[5]), pack_l(x[6], x[7])};
    const int slot = ((pkpl << 2) + pkq) ^ (pkpx & 7);
    *(u32x4*)(&bfmt[dq][kk][pkpx * 128 + slot * 16]) = outv;
  };
  auto gemmstep = [&](int sq, int kk, bf16x8 (*pa)[2]) {
    bf16x8 bH[2], bL[2];
#pragma unroll
    for (int n = 0; n < 2; ++n) {
      const int r = wc * 32 + n * 16 + fr;
      const char* rp = &bfmt[sq][kk][r * 128];
      bH[n] = *(const bf16x8*)(rp + ((g ^ (r & 7)) << 4));
      bL[n] = *(const bf16x8*)(rp + (((g + 4) ^ (r & 7)) << 4));
    }
#pragma unroll
    for (int m = 0; m < 4; ++m)
#pragma unroll
      for (int n = 0; n < 2; ++n) {
        f32x4 c = acc[m][n];
        MFMA3(c, pa[m][0], pa[m][1], bH[n], bL[n]);
        acc[m][n] = c;
      }
  };

  float4 b0 = bload(0), b1 = bload(1), b2 = bload(2), b3 = bload(3);
  float4 blE0 = bload(4), blE1 = bload(5);
  float4 blO0 = bload(6), blO1 = bload(7);
  aload(0, paA);
  aload(1, paB);

  bf32w(0, b0); bf32w(1, b1);
  LGKM_BAR();
  pack(0, 0); pack(1, 0);
  LGKM_BAR();
  bf32w(0, b2); bf32w(1, b3);
  LGKM_BAR();

  for (int pp = 0; pp < 4; ++pp) {
    const int k4 = 4 * pp;
    gemmstep(0, 0, paA);
    gemmstep(0, 1, paB);
    aload(k4 + 2, paA);
    aload(k4 + 3, paB);
    pack(0, 1); pack(1, 1);
    LGKM_BAR();
    if (pp < 3) { bf32w(0, blE0); bf32w(1, blE1); }
    if (pp < 2) { blE0 = bload(k4 + 8); blE1 = bload(k4 + 9); }
    LGKM_BAR();
    gemmstep(1, 0, paA);
    gemmstep(1, 1, paB);
    if (pp < 3) { aload(k4 + 4, paA); aload(k4 + 5, paB); }
    if (pp < 3) { pack(0, 0); pack(1, 0); }
    LGKM_BAR();
    if (pp < 3) { bf32w(0, blO0); bf32w(1, blO1); }
    if (pp < 2) { blO0 = bload(k4 + 10); blO1 = bload(k4 + 11); }
    LGKM_BAR();
  }

  float* Xp = Xpart + ((size_t)ks * 64 + bz) * 65536;
#pragma unroll
  for (int m = 0; m < 4; ++m) {
    const int gi0 = wr * 64 + m * 16 + g * 4;
#pragma unroll
    for (int n = 0; n < 2; ++n) {
      const int gj = jb + wc * 32 + n * 16 + fr;
#pragma unroll
      for (int j = 0; j < 4; ++j)
        Xp[(size_t)(gi0 + j) * 256 + gj] = acc[m][n][j];
    }
  }
}

// ---------------------------------------------------------------------------
// combine: X = sum of 4 partials + bias -> fmt; mu; trace partials.
__global__ __launch_bounds__(256) void combine_k(
    const float* __restrict__ Xp, const float* __restrict__ bias,
    char* __restrict__ X, float* __restrict__ mu, float* __restrict__ nrm_part)
{
  const int chunk = blockIdx.x, bz = blockIdx.y;
  const int tid = threadIdx.x, lane = tid & 63, w = tid >> 6;
  const float* p0 = Xp + (size_t)bz * 65536;
  char* Xb = X + (size_t)bz * 262144;
  float tracc = 0.f;
#pragma unroll
  for (int i = 0; i < 8; ++i) {
    const int r = chunk * 32 + w * 8 + i;
    const size_t off = (size_t)r * 256 + lane * 4;
    const float4 a = *(const float4*)(p0 + off);
    const float4 b = *(const float4*)(p0 + 64ull * 65536 + off);
    const float4 c = *(const float4*)(p0 + 128ull * 65536 + off);
    const float4 d = *(const float4*)(p0 + 192ull * 65536 + off);
    const float bi = bias[r];
    float v[4] = {a.x + b.x + c.x + d.x + bi, a.y + b.y + c.y + d.y + bi,
                  a.z + b.z + c.z + d.z + bi, a.w + b.w + c.w + d.w + bi};
    float s = v[0] + v[1] + v[2] + v[3];
    float ss = v[0] * v[0] + v[1] * v[1] + v[2] * v[2] + v[3] * v[3];
#pragma unroll
    for (int o = 32; o > 0; o >>= 1) {
      s += __shfl_down(s, o);
      ss += __shfl_down(ss, o);
    }
    const float st = __shfl(s, 0), sst = __shfl(ss, 0);
    const float m = st * (1.f / 256.f);
    if (lane == 0) mu[bz * 256 + r] = m;
    tracc += sst * (1.f / 256.f) - m * m;
    write_quad_g(Xb, r, lane * 4, v);
  }
  __shared__ float red[4];
  if (lane == 0) red[w] = tracc;
  __syncthreads();
  if (tid == 0)
    nrm_part[bz * 8 + chunk] = red[0] + red[1] + red[2] + red[3];
}

__device__ __forceinline__ float nrm_sum(const float* nrmp, int bz) {
  float nv = 0.f;
#pragma unroll
  for (int q = 0; q < 8; ++q) nv += nrmp[bz * 8 + q];
  return nv;
}

// ---------------------------------------------------------------------------
// Column-fused NS kernel, 64-col panels (R14). grid 256 x 512 thr.
// MODE 0 COV : Z0 = 1.5I - 0.5*(cov/nrm) -> outB
// MODE 1 Y0  : Y0 = 3*Z0 - 2*Z0^2 -> outA
// MODE 2 IT  : Yn (outA), Zn (outB)
// MODE 3 FIN : S -> Sf (permuted-linear)
template <int MODE>
__global__ __launch_bounds__(512) void col_k(
    const char* __restrict__ A1, const char* __restrict__ Bsrc,
    const char* __restrict__ Ys, const char* __restrict__ Zs,
    char* __restrict__ outA, char* __restrict__ outB,
    const float* __restrict__ mu, const float* __restrict__ nrmp,
    float* __restrict__ Sf)
{
  __shared__ __align__(16) char Plds[65536];
  const int tid = threadIdx.x, lane = tid & 63, w = tid >> 6;
  const int fr = lane & 15, g = lane >> 4;
  const int blk = blockIdx.x;
  const int bz = (blk & 7) * 8 + ((blk >> 3) & 7);  // XCD batch affinity
  const int jbp = blk >> 6;                          // col panel [0,4)
  const int jb = jbp * 64;
  const size_t MB = 262144;
  const char* Ab = A1 + (size_t)bz * MB;
  const char* Bb = Bsrc + (size_t)bz * MB;
  const int r0 = g * 4;

  f32x4 acc[2][4] = {};
  {
    bf16x8 pa[2][2][2], pb[2][4][2];
#pragma unroll
    for (int par = 0; par < 2; ++par) {
#pragma unroll
      for (int m = 0; m < 2; ++m) {
        const int r = w * 32 + m * 16 + fr;
#pragma unroll
        for (int pl = 0; pl < 2; ++pl) pa[par][m][pl] = *fragp(Ab, par, r, g, pl);
      }
#pragma unroll
      for (int n = 0; n < 4; ++n) {
        const int r = jb + n * 16 + fr;
#pragma unroll
        for (int pl = 0; pl < 2; ++pl) pb[par][n][pl] = *fragp(Bb, par, r, g, pl);
      }
    }
    for (int t2 = 0; t2 < 8; t2 += 2) {
#pragma unroll
      for (int par = 0; par < 2; ++par) {
        const int t = t2 + par;
        bf16x8 aH[2], aL[2], bH[4], bL[4];
#pragma unroll
        for (int m = 0; m < 2; ++m) { aH[m] = pa[par][m][0]; aL[m] = pa[par][m][1]; }
#pragma unroll
        for (int n = 0; n < 4; ++n) { bH[n] = pb[par][n][0]; bL[n] = pb[par][n][1]; }
        if (t + 2 < 8) {
#pragma unroll
          for (int m = 0; m < 2; ++m) {
            const int r = w * 32 + m * 16 + fr;
#pragma unroll
            for (int pl = 0; pl < 2; ++pl)
              pa[par][m][pl] = *fragp(Ab, t + 2, r, g, pl);
          }
#pragma unroll
          for (int n = 0; n < 4; ++n) {
            const int r = jb + n * 16 + fr;
#pragma unroll
            for (int pl = 0; pl < 2; ++pl)
              pb[par][n][pl] = *fragp(Bb, t + 2, r, g, pl);
          }
        }
#pragma unroll
        for (int m = 0; m < 2; ++m)
#pragma unroll
          for (int n = 0; n < 4; ++n) {
            f32x4 c = acc[m][n];
            MFMA3(c, aH[m], aL[m], bH[n], bL[n]);
            acc[m][n] = c;
          }
      }
    }
  }

  if constexpr (MODE == 0) {
    const float rn = 1.0f / nrm_sum(nrmp, bz);
    const float* mub = mu + bz * 256;
    char* oB = outB + (size_t)bz * MB;
#pragma unroll
    for (int m = 0; m < 2; ++m) {
      const int gi0 = w * 32 + m * 16 + r0;
#pragma unroll
      for (int n = 0; n < 4; ++n) {
        const int gj = jb + n * 16 + fr;
        float zz[4];
#pragma unroll
        for (int j = 0; j < 4; ++j) {
          const float v =
              (acc[m][n][j] * (1.f / 256.f) - mub[gi0 + j] * mub[gj]) * rn;
          zz[j] = (gi0 + j == gj ? 1.5f : 0.f) - 0.5f * v;
        }
        write_quad_g(oB, gj, gi0, zz);
      }
    }
  } else if constexpr (MODE == 1) {
    char* oA = outA + (size_t)bz * MB;
#pragma unroll
    for (int m = 0; m < 2; ++m) {
      const int gi0 = w * 32 + m * 16 + r0;
#pragma unroll
      for (int n = 0; n < 4; ++n) {
        const int gj = jb + n * 16 + fr;
        float zv[4], vv[4];
        read_quad_g(Bb, gj, gi0, zv);
#pragma unroll
        for (int j = 0; j < 4; ++j) vv[j] = 3.f * zv[j] - 2.f * acc[m][n][j];
        write_quad_g(oA, gj, gi0, vv);
      }
    }
  } else {
#pragma unroll
    for (int m = 0; m < 2; ++m) {
      const int gi0 = w * 32 + m * 16 + r0;
#pragma unroll
      for (int n = 0; n < 4; ++n) {
        const int jl = n * 16 + fr;
        float vv[4] = {acc[m][n][0], acc[m][n][1], acc[m][n][2], acc[m][n][3]};
        write_quad_l(Plds, jl, gi0, vv);
      }
    }
    const char* Yb = Ys + (size_t)bz * MB;
    const char* Zb = (MODE == 2) ? (Zs + (size_t)bz * MB) : nullptr;
    bf16x8 py[2][2][2], pz[2][2][2];
#pragma unroll
    for (int par = 0; par < 2; ++par)
#pragma unroll
      for (int m = 0; m < 2; ++m) {
        const int r = w * 32 + m * 16 + fr;
#pragma unroll
        for (int pl = 0; pl < 2; ++pl) {
          py[par][m][pl] = *fragp(Yb, par, r, g, pl);
          if constexpr (MODE == 2) pz[par][m][pl] = *fragp(Zb, par, r, g, pl);
        }
      }
    __syncthreads();

    f32x4 aY[2][4] = {}, aZ[2][4] = {};
    for (int t2 = 0; t2 < 8; t2 += 2) {
#pragma unroll
      for (int par = 0; par < 2; ++par) {
        const int t = t2 + par;
        bf16x8 yH[2], yL[2], zH[2], zL[2];
#pragma unroll
        for (int m = 0; m < 2; ++m) {
          yH[m] = py[par][m][0]; yL[m] = py[par][m][1];
          if constexpr (MODE == 2) { zH[m] = pz[par][m][0]; zL[m] = pz[par][m][1]; }
        }
        if (t + 2 < 8) {
#pragma unroll
          for (int m = 0; m < 2; ++m) {
            const int r = w * 32 + m * 16 + fr;
#pragma unroll
            for (int pl = 0; pl < 2; ++pl) {
              py[par][m][pl] = *fragp(Yb, t + 2, r, g, pl);
              if constexpr (MODE == 2) pz[par][m][pl] = *fragp(Zb, t + 2, r, g, pl);
            }
          }
        }
        bf16x8 bH[4], bL[4];
#pragma unroll
        for (int n = 0; n < 4; ++n) {
          const int jl = n * 16 + fr;
          bH[n] = *fragl(Plds, t, jl, g, 0);
          bL[n] = *fragl(Plds, t, jl, g, 1);
        }
#pragma unroll
        for (int m = 0; m < 2; ++m)
#pragma unroll
          for (int n = 0; n < 4; ++n) {
            f32x4 cy = aY[m][n];
            MFMA3(cy, yH[m], yL[m], bH[n], bL[n]);
            aY[m][n] = cy;
            if constexpr (MODE == 2) {
              f32x4 cz = aZ[m][n];
              MFMA3(cz, zH[m], zL[m], bH[n], bL[n]);
              aZ[m][n] = cz;
            }
          }
      }
    }
    if constexpr (MODE == 2) {
      char* oA = outA + (size_t)bz * MB;
      char* oB = outB + (size_t)bz * MB;
#pragma unroll
      for (int m = 0; m < 2; ++m) {
        const int gi0 = w * 32 + m * 16 + r0;
#pragma unroll
        for (int n = 0; n < 4; ++n) {
          const int gj = jb + n * 16 + fr;
          float base[4], vv[4];
          read_quad_g(Yb, gj, gi0, base);
#pragma unroll
          for (int j = 0; j < 4; ++j) vv[j] = 1.5f * base[j] - 0.5f * aY[m][n][j];
          write_quad_g(oA, gj, gi0, vv);
          read_quad_g(Zb, gj, gi0, base);
#pragma unroll
          for (int j = 0; j < 4; ++j) vv[j] = 1.5f * base[j] - 0.5f * aZ[m][n][j];
          write_quad_g(oB, gj, gi0, vv);
        }
      }
    } else {
      const float sq = sqrtf(nrm_sum(nrmp, bz));
      float* Sb = Sf + (size_t)bz * 65536 + (size_t)jbp * 16384 + (size_t)tid * 32;
#pragma unroll
      for (int m = 0; m < 2; ++m) {
        const int gi0 = w * 32 + m * 16 + r0;
#pragma unroll
        for (int n = 0; n < 4; ++n) {
          const int gj = jb + n * 16 + fr;
          float base[4];
          read_quad_g(Yb, gj, gi0, base);
          f32x4 vv;
#pragma unroll
          for (int j = 0; j < 4; ++j)
            vv[j] = (1.5f * base[j] - 0.5f * aY[m][n][j]) * sq;
          *(f32x4*)(Sb + m * 16 + n * 4) = vv;
        }
      }
    }
  }
}

// ---------------------------------------------------------------------------
// Heads: out[b,v] = dot(S_b, W2_v) + bias (identical permuted layouts).
__global__ __launch_bounds__(256) void head2(
    const float* __restrict__ Sf, const float* __restrict__ W2,
    const float* __restrict__ b_type, const float* __restrict__ b_flag,
    float* __restrict__ out)
{
  const int b = blockIdx.x, v = blockIdx.y, tid = threadIdx.x;
  const float4* s4 = (const float4*)(Sf + (size_t)b * 65536);
  const float4* w4 = (const float4*)(W2 + (size_t)v * 65536);
  float acc = 0.f;
  for (int i = tid; i < 16384; i += 256) {
    const float4 a = s4[i], c = w4[i];
    acc += a.x * c.x + a.y * c.y + a.z * c.z + a.w * c.w;
  }
  __shared__ float red[256];
  red[tid] = acc;
  __syncthreads();
  for (int o = 128; o > 0; o >>= 1) {
    if (tid < o) red[tid] += red[tid + o];
    __syncthreads();
  }
  if (tid == 0) {
    if (v < 4) out[b * 4 + v] = red[0] + b_type[v];
    else       out[256 + b] = red[0] + b_flag[0];
  }
}

// ---------------------------------------------------------------------------
extern "C" void kernel_launch(void* const* d_in, const int* in_sizes, int n_in,
                              void* d_out, int out_size, void* d_ws, size_t ws_size,
                              hipStream_t stream)
{
  const float* features = (const float*)d_in[0];
  const float* w_bn     = (const float*)d_in[1];
  const float* b_bn     = (const float*)d_in[2];
  const float* w_type   = (const float*)d_in[3];
  const float* b_type   = (const float*)d_in[4];
  const float* w_flag   = (const float*)d_in[5];
  const float* b_flag   = (const float*)d_in[6];
  float* out = (float*)d_out;

  char* W = (char*)d_ws;
  const size_t PB = 16777216;
  char* P0 = W;           char* P1 = W + PB;     char* P2 = W + 2 * PB;
  char* P3 = W + 3 * PB;  char* P4 = W + 4 * PB;
  char* Wf = W + 5 * PB;                          // 2 MB
  float* W2 = (float*)(W + 5 * PB + 2097152);     // 1.31 MB
  float* mu = (float*)(W + 5 * PB + 4194304);     // 64 KB
  float* nrm_part = mu + 16384;                   // 512 floats
  float* Xpart = (float*)(W + 5 * PB + 8388608);  // 4 x 16.78 MB
  float* Sf = (float*)P4;                         // final S fp32 (P4 free)

  prep_k<<<dim3(144), dim3(256), 0, stream>>>(w_bn, w_type, w_flag, Wf, W2);
  conv6b_k<<<dim3(4, 64, 4), dim3(512), 0, stream>>>(Wf, features, Xpart);
  combine_k<<<dim3(8, 64), dim3(256), 0, stream>>>(Xpart, b_bn, P0, mu, nrm_part);

  const dim3 cg(256), cb(512);
  // cov: Z0 = 1.5I - 0.5*An -> P2   (X = P0)
  col_k<0><<<cg, cb, 0, stream>>>(P0, P0, nullptr, nullptr, nullptr, P2, mu, nrm_part, nullptr);
  // Y0 = 3*Z0 - 2*Z0^2 -> P3
  col_k<1><<<cg, cb, 0, stream>>>(P2, P2, nullptr, nullptr, P3, nullptr, nullptr, nullptr, nullptr);
  // it1: Z=P2, Y=P3 -> Yn P0, Zn P1
  col_k<2><<<cg, cb, 0, stream>>>(P2, P3, P3, P2, P0, P1, nullptr, nullptr, nullptr);
  // it2: Z=P1, Y=P0 -> Yn P3, Zn P2
  col_k<2><<<cg, cb, 0, stream>>>(P1, P0, P0, P1, P3, P2, nullptr, nullptr, nullptr);
  // it3: Z=P2, Y=P3 -> Yn P1, Zn P0
  col_k<2><<<cg, cb, 0, stream>>>(P2, P3, P3, P2, P1, P0, nullptr, nullptr, nullptr);
  // fin: Z=P0, Y=P1 -> Sf (permuted-linear)
  col_k<3><<<cg, cb, 0, stream>>>(P0, P1, P1, nullptr, nullptr, nullptr, nullptr, nrm_part, Sf);

  head2<<<dim3(64, 5), dim3(256), 0, stream>>>(Sf, W2, b_type, b_flag, out);
  (void)in_sizes; (void)n_in; (void)out_size; (void)ws_size;
}

// Round 19
// 268.250 us; speedup vs baseline: 2.0042x; 1.0807x over previous
//
#include <hip/hip_runtime.h>
#include <math.h>

// ---------------------------------------------------------------------------
// HPFNetCovPool round 19 = exact restore of R14 (best measured: 269us,
// absmax 1.95e-3). R15-R18 experiments (cooperative chain fusion, conv
// K-split, VGPR cap) all regressed or failed; this is the converged config:
//   conv6_k (ks=2, 92 VGPR, 2 blocks/CU) + 6-dispatch NS chain (64-col
//   panels, An-eliminated via Y0 = 3*Z0 - 2*Z0^2, permuted-linear S store)
//   + prep/combine/head2.
// fmt storage: [batch][kt=k/32][row(256)][128B]; 128B = 8x16B slots,
// slot_log = plane*4 + ((k&31)>>3), stored at slot_log ^ (row&7).
// ---------------------------------------------------------------------------

typedef __attribute__((ext_vector_type(8))) short bf16x8;
typedef __attribute__((ext_vector_type(4))) float f32x4;
typedef __attribute__((ext_vector_type(4))) unsigned u32x4;
typedef __attribute__((ext_vector_type(2))) unsigned u32x2;

__device__ __forceinline__ unsigned fbits(float f) { union { float f; unsigned u; } x; x.f = f; return x.u; }
__device__ __forceinline__ float bitsf(unsigned u) { union { float f; unsigned u; } x; x.u = u; return x.f; }

__device__ __forceinline__ unsigned pack_h(float a, float b) {
  return (fbits(a) >> 16) | (fbits(b) & 0xFFFF0000u);
}
__device__ __forceinline__ unsigned pack_l(float a, float b) {
  float la = a - bitsf(fbits(a) & 0xFFFF0000u);
  float lb = b - bitsf(fbits(b) & 0xFFFF0000u);
  return (fbits(la) >> 16) | (fbits(lb) & 0xFFFF0000u);
}

__device__ __forceinline__ const bf16x8* fragp(const char* M, int kt, int row,
                                               int g, int pl) {
  return (const bf16x8*)(M + (size_t)kt * 32768 + (size_t)row * 128 +
                         ((((pl << 2) + g) ^ (row & 7)) << 4));
}
// LDS P-panel (64 rows per kt, stride 8 KB)
__device__ __forceinline__ const bf16x8* fragl(const char* L, int kt, int row,
                                               int g, int pl) {
  return (const bf16x8*)(L + kt * 8192 + row * 128 +
                         ((((pl << 2) + g) ^ (row & 7)) << 4));
}

__device__ __forceinline__ void write_quad_g(char* M, int row, int k0,
                                             const float* v) {
  char* rp = M + (size_t)(k0 >> 5) * 32768 + (size_t)row * 128;
  const int s = (k0 & 31) >> 3, bo = (k0 & 7) * 2;
  *(u32x2*)(rp + (((s) ^ (row & 7)) << 4) + bo) =
      (u32x2){pack_h(v[0], v[1]), pack_h(v[2], v[3])};
  *(u32x2*)(rp + (((s + 4) ^ (row & 7)) << 4) + bo) =
      (u32x2){pack_l(v[0], v[1]), pack_l(v[2], v[3])};
}
__device__ __forceinline__ void write_quad_l(char* L, int row, int k0,
                                             const float* v) {
  char* rp = L + (k0 >> 5) * 8192 + row * 128;
  const int s = (k0 & 31) >> 3, bo = (k0 & 7) * 2;
  *(u32x2*)(rp + (((s) ^ (row & 7)) << 4) + bo) =
      (u32x2){pack_h(v[0], v[1]), pack_h(v[2], v[3])};
  *(u32x2*)(rp + (((s + 4) ^ (row & 7)) << 4) + bo) =
      (u32x2){pack_l(v[0], v[1]), pack_l(v[2], v[3])};
}
__device__ __forceinline__ void read_quad_g(const char* M, int row, int k0,
                                            float* v) {
  const char* rp = M + (size_t)(k0 >> 5) * 32768 + (size_t)row * 128;
  const int s = (k0 & 31) >> 3, bo = (k0 & 7) * 2;
  const u32x2 hq = *(const u32x2*)(rp + (((s) ^ (row & 7)) << 4) + bo);
  const u32x2 lq = *(const u32x2*)(rp + (((s + 4) ^ (row & 7)) << 4) + bo);
  v[0] = bitsf(hq[0] << 16) + bitsf(lq[0] << 16);
  v[1] = bitsf(hq[0] & 0xFFFF0000u) + bitsf(lq[0] & 0xFFFF0000u);
  v[2] = bitsf(hq[1] << 16) + bitsf(lq[1] << 16);
  v[3] = bitsf(hq[1] & 0xFFFF0000u) + bitsf(lq[1] & 0xFFFF0000u);
}

#define MFMA3(c, aH, aL, bH, bL)                                            \
  c = __builtin_amdgcn_mfma_f32_16x16x32_bf16(aL, bH, c, 0, 0, 0);          \
  c = __builtin_amdgcn_mfma_f32_16x16x32_bf16(aH, bL, c, 0, 0, 0);          \
  c = __builtin_amdgcn_mfma_f32_16x16x32_bf16(aH, bH, c, 0, 0, 0);

#define LGKM_BAR() do { asm volatile("s_waitcnt lgkmcnt(0)" ::: "memory"); \
                        __builtin_amdgcn_s_barrier(); } while (0)

// ---------------------------------------------------------------------------
// prep: [0,64) w_bn->Wf fmt ; [64,144) build W2 permuted to match col_k MODE3.
// slot s = jbp*16384 + tid*32 + m*16 + n*4 + j  (tid in [0,512))
//   i = (tid>>6)*32 + m*16 + ((tid&63)>>4)*4 + j
//   jcol = jbp*64 + n*16 + (tid&15)
__global__ __launch_bounds__(256) void prep_k(
    const float* __restrict__ w_bn, const float* __restrict__ w_type,
    const float* __restrict__ w_flag, char* __restrict__ Wf,
    float* __restrict__ W2)
{
  const int bid = blockIdx.x;
  if (bid < 64) {
    const int kt = bid, r = threadIdx.x;
    const float* src = w_bn + (size_t)r * 2048 + kt * 32;
    char* rp = Wf + (size_t)kt * 32768 + (size_t)r * 128;
#pragma unroll
    for (int s = 0; s < 4; ++s) {
      float x[8];
#pragma unroll
      for (int e = 0; e < 8; ++e) x[e] = src[s * 8 + e];
      *(u32x4*)(rp + ((s ^ (r & 7)) << 4)) =
          (u32x4){pack_h(x[0], x[1]), pack_h(x[2], x[3]),
                  pack_h(x[4], x[5]), pack_h(x[6], x[7])};
      *(u32x4*)(rp + (((s + 4) ^ (r & 7)) << 4)) =
          (u32x4){pack_l(x[0], x[1]), pack_l(x[2], x[3]),
                  pack_l(x[4], x[5]), pack_l(x[6], x[7])};
    }
  } else {
    const int idx = bid - 64;          // [0,80)
    const int v = idx >> 4, chunk = idx & 15;
    const float* src = (v < 4) ? (w_type + (size_t)v * 32896) : w_flag;
    const int s0 = chunk * 4096 + threadIdx.x * 16;
    float outv[16];
#pragma unroll
    for (int q = 0; q < 16; ++q) {
      const int s = s0 + q;
      const int jbp = s >> 14, r = s & 16383;
      const int ttid = r >> 5, qq = r & 31;
      const int m = qq >> 4, n = (qq >> 2) & 3, jj = qq & 3;
      const int ww = ttid >> 6, ll = ttid & 63;
      const int i = ww * 32 + m * 16 + (ll >> 4) * 4 + jj;
      const int jcol = jbp * 64 + n * 16 + (ll & 15);
      const int rr = i < jcol ? i : jcol, cc = i < jcol ? jcol : i;
      const int t = rr * 256 - (rr * (rr - 1)) / 2 + (cc - rr);
      outv[q] = src[t] * (i == jcol ? 1.0f : 0.5f);
    }
    float* dst = W2 + (size_t)v * 65536 + s0;
#pragma unroll
    for (int q = 0; q < 4; ++q)
      *(f32x4*)(dst + q * 4) = *(f32x4*)(outv + q * 4);
  }
}

// ---------------------------------------------------------------------------
// conv6 (R10, best measured): partial X = Wf[kt half] @ F^T, fused transpose.
__global__ __launch_bounds__(512) void conv6_k(
    const char* __restrict__ Wf, const float* __restrict__ F,
    float* __restrict__ Xpart)
{
  __shared__ float bf32s[2][64 * 33];
  __shared__ __align__(16) char bfmt[2][2][8192];

  const int tid = threadIdx.x, lane = tid & 63, w = tid >> 6;
  const int wr = w >> 1, wc = w & 1, fr = lane & 15, g = lane >> 4;
  const int jb = blockIdx.x * 64, bz = blockIdx.y, ks = blockIdx.z;
  const int kb = ks * 32;
  const float* Fb = F + (size_t)bz * 524288;

  const int blc = tid >> 4, blpx = (tid & 15) * 4;
  const int pkpx = tid >> 3, pkq = tid & 3, pkpl = (tid >> 2) & 1;

  f32x4 acc[4][2] = {};
  bf16x8 paA[4][2], paB[4][2];

  auto bload = [&](int t) -> float4 {
    return *(const float4*)(Fb + ((size_t)(kb + t) * 32 + blc) * 256 + jb + blpx);
  };
  auto bf32w = [&](int kk, const float4& r) {
    float* p = &bf32s[kk][0];
    p[(blpx + 0) * 33 + blc] = r.x;
    p[(blpx + 1) * 33 + blc] = r.y;
    p[(blpx + 2) * 33 + blc] = r.z;
    p[(blpx + 3) * 33 + blc] = r.w;
  };
  auto aload = [&](int t, bf16x8 (*pa)[2]) {
#pragma unroll
    for (int m = 0; m < 4; ++m) {
      const int r = wr * 64 + m * 16 + fr;
#pragma unroll
      for (int pl = 0; pl < 2; ++pl) pa[m][pl] = *fragp(Wf, kb + t, r, g, pl);
    }
  };
  auto pack = [&](int kk, int dq) {
    const float* p = &bf32s[kk][pkpx * 33 + pkq * 8];
    float x[8];
#pragma unroll
    for (int e = 0; e < 8; ++e) x[e] = p[e];
    u32x4 outv;
    if (pkpl == 0)
      outv = (u32x4){pack_h(x[0], x[1]), pack_h(x[2], x[3]),
                     pack_h(x[4], x[5]), pack_h(x[6], x[7])};
    else
      outv = (u32x4){pack_l(x[0], x[1]), pack_l(x[2], x[3]),
                     pack_l(x[4], x[5]), pack_l(x[6], x[7])};
    const int slot = ((pkpl << 2) + pkq) ^ (pkpx & 7);
    *(u32x4*)(&bfmt[dq][kk][pkpx * 128 + slot * 16]) = outv;
  };
  auto gemmstep = [&](int sq, int kk, bf16x8 (*pa)[2]) {
    bf16x8 bH[2], bL[2];
#pragma unroll
    for (int n = 0; n < 2; ++n) {
      const int r = wc * 32 + n * 16 + fr;
      const char* rp = &bfmt[sq][kk][r * 128];
      bH[n] = *(const bf16x8*)(rp + ((g ^ (r & 7)) << 4));
      bL[n] = *(const bf16x8*)(rp + (((g + 4) ^ (r & 7)) << 4));
    }
#pragma unroll
    for (int m = 0; m < 4; ++m)
#pragma unroll
      for (int n = 0; n < 2; ++n) {
        f32x4 c = acc[m][n];
        MFMA3(c, pa[m][0], pa[m][1], bH[n], bL[n]);
        acc[m][n] = c;
      }
  };

  float4 b0 = bload(0), b1 = bload(1), b2 = bload(2), b3 = bload(3);
  float4 blE0 = bload(4), blE1 = bload(5);
  float4 blO0 = bload(6), blO1 = bload(7);
  aload(0, paA);
  aload(1, paB);

  bf32w(0, b0); bf32w(1, b1);
  LGKM_BAR();
  pack(0, 0); pack(1, 0);
  LGKM_BAR();
  bf32w(0, b2); bf32w(1, b3);
  LGKM_BAR();

  for (int pp = 0; pp < 8; ++pp) {
    const int k4 = 4 * pp;
    gemmstep(0, 0, paA);
    gemmstep(0, 1, paB);
    aload(k4 + 2, paA);
    aload(k4 + 3, paB);
    pack(0, 1); pack(1, 1);
    LGKM_BAR();
    if (pp < 7) { bf32w(0, blE0); bf32w(1, blE1); }
    if (pp < 6) { blE0 = bload(k4 + 8); blE1 = bload(k4 + 9); }
    LGKM_BAR();
    gemmstep(1, 0, paA);
    gemmstep(1, 1, paB);
    if (pp < 7) { aload(k4 + 4, paA); aload(k4 + 5, paB); }
    if (pp < 7) { pack(0, 0); pack(1, 0); }
    LGKM_BAR();
    if (pp < 7) { bf32w(0, blO0); bf32w(1, blO1); }
    if (pp < 6) { blO0 = bload(k4 + 10); blO1 = bload(k4 + 11); }
    LGKM_BAR();
  }

  float* Xp = Xpart + ((size_t)ks * 64 + bz) * 65536;
#pragma unroll
  for (int m = 0; m < 4; ++m) {
    const int gi0 = wr * 64 + m * 16 + g * 4;
#pragma unroll
    for (int n = 0; n < 2; ++n) {
      const int gj = jb + wc * 32 + n * 16 + fr;
#pragma unroll
      for (int j = 0; j < 4; ++j)
        Xp[(size_t)(gi0 + j) * 256 + gj] = acc[m][n][j];
    }
  }
}

// ---------------------------------------------------------------------------
// combine: X = Xp0 + Xp1 + bias -> fmt; mu; per-chunk trace partials.
__global__ __launch_bounds__(256) void combine_k(
    const float* __restrict__ Xp0, const float* __restrict__ Xp1,
    const float* __restrict__ bias, char* __restrict__ X,
    float* __restrict__ mu, float* __restrict__ nrm_part)
{
  const int chunk = blockIdx.x, bz = blockIdx.y;
  const int tid = threadIdx.x, lane = tid & 63, w = tid >> 6;
  const float* p0 = Xp0 + (size_t)bz * 65536;
  const float* p1 = Xp1 + (size_t)bz * 65536;
  char* Xb = X + (size_t)bz * 262144;
  float tracc = 0.f;
#pragma unroll
  for (int i = 0; i < 8; ++i) {
    const int r = chunk * 32 + w * 8 + i;
    const float4 a = *(const float4*)(p0 + (size_t)r * 256 + lane * 4);
    const float4 b = *(const float4*)(p1 + (size_t)r * 256 + lane * 4);
    const float bi = bias[r];
    float v[4] = {a.x + b.x + bi, a.y + b.y + bi,
                  a.z + b.z + bi, a.w + b.w + bi};
    float s = v[0] + v[1] + v[2] + v[3];
    float ss = v[0] * v[0] + v[1] * v[1] + v[2] * v[2] + v[3] * v[3];
#pragma unroll
    for (int o = 32; o > 0; o >>= 1) {
      s += __shfl_down(s, o);
      ss += __shfl_down(ss, o);
    }
    const float st = __shfl(s, 0), sst = __shfl(ss, 0);
    const float m = st * (1.f / 256.f);
    if (lane == 0) mu[bz * 256 + r] = m;
    tracc += sst * (1.f / 256.f) - m * m;
    write_quad_g(Xb, r, lane * 4, v);
  }
  __shared__ float red[4];
  if (lane == 0) red[w] = tracc;
  __syncthreads();
  if (tid == 0)
    nrm_part[bz * 8 + chunk] = red[0] + red[1] + red[2] + red[3];
}

__device__ __forceinline__ float nrm_sum(const float* nrmp, int bz) {
  float nv = 0.f;
#pragma unroll
  for (int q = 0; q < 8; ++q) nv += nrmp[bz * 8 + q];
  return nv;
}

// ---------------------------------------------------------------------------
// Column-fused NS kernel, 64-col panels (R12 geometry). grid 256 x 512 thr.
// MODE 0 COV : Z0 = 1.5I - 0.5*(cov/nrm) -> outB  (An never materialized)
// MODE 1 Y0  : stage1 = Z0^2 panel; Y0 = 3*Z0 - 2*Z0^2 -> outA
// MODE 2 IT  : stage1 P = Z@Y[:,c] -> LDS; Yn=1.5Y-0.5Y@P (outA), Zn (outB)
// MODE 3 FIN : stage1 P -> LDS; S = (1.5Y - 0.5Y@P)*sqrt(nrm) -> Sf permuted
template <int MODE>
__global__ __launch_bounds__(512) void col_k(
    const char* __restrict__ A1, const char* __restrict__ Bsrc,
    const char* __restrict__ Ys, const char* __restrict__ Zs,
    char* __restrict__ outA, char* __restrict__ outB,
    const float* __restrict__ mu, const float* __restrict__ nrmp,
    float* __restrict__ Sf)
{
  __shared__ __align__(16) char Plds[65536];
  const int tid = threadIdx.x, lane = tid & 63, w = tid >> 6;
  const int fr = lane & 15, g = lane >> 4;
  const int blk = blockIdx.x;
  const int bz = (blk & 7) * 8 + ((blk >> 3) & 7);  // XCD batch affinity
  const int jbp = blk >> 6;                          // col panel [0,4)
  const int jb = jbp * 64;
  const size_t MB = 262144;
  const char* Ab = A1 + (size_t)bz * MB;
  const char* Bb = Bsrc + (size_t)bz * MB;
  const int r0 = g * 4;

  f32x4 acc[2][4] = {};
  {
    bf16x8 pa[2][2][2], pb[2][4][2];
#pragma unroll
    for (int par = 0; par < 2; ++par) {
#pragma unroll
      for (int m = 0; m < 2; ++m) {
        const int r = w * 32 + m * 16 + fr;
#pragma unroll
        for (int pl = 0; pl < 2; ++pl) pa[par][m][pl] = *fragp(Ab, par, r, g, pl);
      }
#pragma unroll
      for (int n = 0; n < 4; ++n) {
        const int r = jb + n * 16 + fr;
#pragma unroll
        for (int pl = 0; pl < 2; ++pl) pb[par][n][pl] = *fragp(Bb, par, r, g, pl);
      }
    }
    for (int t2 = 0; t2 < 8; t2 += 2) {
#pragma unroll
      for (int par = 0; par < 2; ++par) {
        const int t = t2 + par;
        bf16x8 aH[2], aL[2], bH[4], bL[4];
#pragma unroll
        for (int m = 0; m < 2; ++m) { aH[m] = pa[par][m][0]; aL[m] = pa[par][m][1]; }
#pragma unroll
        for (int n = 0; n < 4; ++n) { bH[n] = pb[par][n][0]; bL[n] = pb[par][n][1]; }
        if (t + 2 < 8) {
#pragma unroll
          for (int m = 0; m < 2; ++m) {
            const int r = w * 32 + m * 16 + fr;
#pragma unroll
            for (int pl = 0; pl < 2; ++pl)
              pa[par][m][pl] = *fragp(Ab, t + 2, r, g, pl);
          }
#pragma unroll
          for (int n = 0; n < 4; ++n) {
            const int r = jb + n * 16 + fr;
#pragma unroll
            for (int pl = 0; pl < 2; ++pl)
              pb[par][n][pl] = *fragp(Bb, t + 2, r, g, pl);
          }
        }
#pragma unroll
        for (int m = 0; m < 2; ++m)
#pragma unroll
          for (int n = 0; n < 4; ++n) {
            f32x4 c = acc[m][n];
            MFMA3(c, aH[m], aL[m], bH[n], bL[n]);
            acc[m][n] = c;
          }
      }
    }
  }

  if constexpr (MODE == 0) {
    const float rn = 1.0f / nrm_sum(nrmp, bz);
    const float* mub = mu + bz * 256;
    char* oB = outB + (size_t)bz * MB;
#pragma unroll
    for (int m = 0; m < 2; ++m) {
      const int gi0 = w * 32 + m * 16 + r0;
#pragma unroll
      for (int n = 0; n < 4; ++n) {
        const int gj = jb + n * 16 + fr;
        float zz[4];
#pragma unroll
        for (int j = 0; j < 4; ++j) {
          const float v =
              (acc[m][n][j] * (1.f / 256.f) - mub[gi0 + j] * mub[gj]) * rn;
          zz[j] = (gi0 + j == gj ? 1.5f : 0.f) - 0.5f * v;
        }
        write_quad_g(oB, gj, gi0, zz);
      }
    }
  } else if constexpr (MODE == 1) {
    // Y0 = 3*Z0 - 2*Z0^2  (An = 3I - 2Z0 never materialized)
    char* oA = outA + (size_t)bz * MB;
#pragma unroll
    for (int m = 0; m < 2; ++m) {
      const int gi0 = w * 32 + m * 16 + r0;
#pragma unroll
      for (int n = 0; n < 4; ++n) {
        const int gj = jb + n * 16 + fr;
        float zv[4], vv[4];
        read_quad_g(Bb, gj, gi0, zv);
#pragma unroll
        for (int j = 0; j < 4; ++j) vv[j] = 3.f * zv[j] - 2.f * acc[m][n][j];
        write_quad_g(oA, gj, gi0, vv);
      }
    }
  } else {
    // pack P^T panel into LDS fmt
#pragma unroll
    for (int m = 0; m < 2; ++m) {
      const int gi0 = w * 32 + m * 16 + r0;
#pragma unroll
      for (int n = 0; n < 4; ++n) {
        const int jl = n * 16 + fr;
        float vv[4] = {acc[m][n][0], acc[m][n][1], acc[m][n][2], acc[m][n][3]};
        write_quad_l(Plds, jl, gi0, vv);
      }
    }
    // stage2 Y/Z initial prefetch hoisted above the sync
    const char* Yb = Ys + (size_t)bz * MB;
    const char* Zb = (MODE == 2) ? (Zs + (size_t)bz * MB) : nullptr;
    bf16x8 py[2][2][2], pz[2][2][2];
#pragma unroll
    for (int par = 0; par < 2; ++par)
#pragma unroll
      for (int m = 0; m < 2; ++m) {
        const int r = w * 32 + m * 16 + fr;
#pragma unroll
        for (int pl = 0; pl < 2; ++pl) {
          py[par][m][pl] = *fragp(Yb, par, r, g, pl);
          if constexpr (MODE == 2) pz[par][m][pl] = *fragp(Zb, par, r, g, pl);
        }
      }
    __syncthreads();

    f32x4 aY[2][4] = {}, aZ[2][4] = {};
    for (int t2 = 0; t2 < 8; t2 += 2) {
#pragma unroll
      for (int par = 0; par < 2; ++par) {
        const int t = t2 + par;
        bf16x8 yH[2], yL[2], zH[2], zL[2];
#pragma unroll
        for (int m = 0; m < 2; ++m) {
          yH[m] = py[par][m][0]; yL[m] = py[par][m][1];
          if constexpr (MODE == 2) { zH[m] = pz[par][m][0]; zL[m] = pz[par][m][1]; }
        }
        if (t + 2 < 8) {
#pragma unroll
          for (int m = 0; m < 2; ++m) {
            const int r = w * 32 + m * 16 + fr;
#pragma unroll
            for (int pl = 0; pl < 2; ++pl) {
              py[par][m][pl] = *fragp(Yb, t + 2, r, g, pl);
              if constexpr (MODE == 2) pz[par][m][pl] = *fragp(Zb, t + 2, r, g, pl);
            }
          }
        }
        bf16x8 bH[4], bL[4];
#pragma unroll
        for (int n = 0; n < 4; ++n) {
          const int jl = n * 16 + fr;
          bH[n] = *fragl(Plds, t, jl, g, 0);
          bL[n] = *fragl(Plds, t, jl, g, 1);
        }
#pragma unroll
        for (int m = 0; m < 2; ++m)
#pragma unroll
          for (int n = 0; n < 4; ++n) {
            f32x4 cy = aY[m][n];
            MFMA3(cy, yH[m], yL[m], bH[n], bL[n]);
            aY[m][n] = cy;
            if constexpr (MODE == 2) {
              f32x4 cz = aZ[m][n];
              MFMA3(cz, zH[m], zL[m], bH[n], bL[n]);
              aZ[m][n] = cz;
            }
          }
      }
    }
    if constexpr (MODE == 2) {
      char* oA = outA + (size_t)bz * MB;
      char* oB = outB + (size_t)bz * MB;
#pragma unroll
      for (int m = 0; m < 2; ++m) {
        const int gi0 = w * 32 + m * 16 + r0;
#pragma unroll
        for (int n = 0; n < 4; ++n) {
          const int gj = jb + n * 16 + fr;
          float base[4], vv[4];
          read_quad_g(Yb, gj, gi0, base);
#pragma unroll
          for (int j = 0; j < 4; ++j) vv[j] = 1.5f * base[j] - 0.5f * aY[m][n][j];
          write_quad_g(oA, gj, gi0, vv);
          read_quad_g(Zb, gj, gi0, base);
#pragma unroll
          for (int j = 0; j < 4; ++j) vv[j] = 1.5f * base[j] - 0.5f * aZ[m][n][j];
          write_quad_g(oB, gj, gi0, vv);
        }
      }
    } else {
      // MODE 3: permuted-linear coalesced S store (matches prep_k's W2 perm)
      const float sq = sqrtf(nrm_sum(nrmp, bz));
      float* Sb = Sf + (size_t)bz * 65536 + (size_t)jbp * 16384 + (size_t)tid * 32;
#pragma unroll
      for (int m = 0; m < 2; ++m) {
        const int gi0 = w * 32 + m * 16 + r0;
#pragma unroll
        for (int n = 0; n < 4; ++n) {
          const int gj = jb + n * 16 + fr;
          float base[4];
          read_quad_g(Yb, gj, gi0, base);
          f32x4 vv;
#pragma unroll
          for (int j = 0; j < 4; ++j)
            vv[j] = (1.5f * base[j] - 0.5f * aY[m][n][j]) * sq;
          *(f32x4*)(Sb + m * 16 + n * 4) = vv;
        }
      }
    }
  }
}

// ---------------------------------------------------------------------------
// Heads: out[b,v] = dot(S_b, W2_v) + bias (identical permuted layouts).
__global__ __launch_bounds__(256) void head2(
    const float* __restrict__ Sf, const float* __restrict__ W2,
    const float* __restrict__ b_type, const float* __restrict__ b_flag,
    float* __restrict__ out)
{
  const int b = blockIdx.x, v = blockIdx.y, tid = threadIdx.x;
  const float4* s4 = (const float4*)(Sf + (size_t)b * 65536);
  const float4* w4 = (const float4*)(W2 + (size_t)v * 65536);
  float acc = 0.f;
  for (int i = tid; i < 16384; i += 256) {
    const float4 a = s4[i], c = w4[i];
    acc += a.x * c.x + a.y * c.y + a.z * c.z + a.w * c.w;
  }
  __shared__ float red[256];
  red[tid] = acc;
  __syncthreads();
  for (int o = 128; o > 0; o >>= 1) {
    if (tid < o) red[tid] += red[tid + o];
    __syncthreads();
  }
  if (tid == 0) {
    if (v < 4) out[b * 4 + v] = red[0] + b_type[v];
    else       out[256 + b] = red[0] + b_flag[0];
  }
}

// ---------------------------------------------------------------------------
extern "C" void kernel_launch(void* const* d_in, const int* in_sizes, int n_in,
                              void* d_out, int out_size, void* d_ws, size_t ws_size,
                              hipStream_t stream)
{
  const float* features = (const float*)d_in[0];
  const float* w_bn     = (const float*)d_in[1];
  const float* b_bn     = (const float*)d_in[2];
  const float* w_type   = (const float*)d_in[3];
  const float* b_type   = (const float*)d_in[4];
  const float* w_flag   = (const float*)d_in[5];
  const float* b_flag   = (const float*)d_in[6];
  float* out = (float*)d_out;

  char* W = (char*)d_ws;
  const size_t PB = 16777216;
  char* P0 = W;           char* P1 = W + PB;     char* P2 = W + 2 * PB;
  char* P3 = W + 3 * PB;  char* P4 = W + 4 * PB;
  char* Wf = W + 5 * PB;                          // 2 MB
  float* W2 = (float*)(W + 5 * PB + 2097152);     // 1.31 MB
  float* mu = (float*)(W + 5 * PB + 4194304);     // 64 KB
  float* nrm_part = mu + 16384;                   // 512 floats
  float* Xpart = (float*)(W + 5 * PB + 8388608);  // 2 x 16.78 MB
  float* Sf = (float*)P4;                         // final S fp32 (P4 dead)

  prep_k<<<dim3(144), dim3(256), 0, stream>>>(w_bn, w_type, w_flag, Wf, W2);
  conv6_k<<<dim3(4, 64, 2), dim3(512), 0, stream>>>(Wf, features, Xpart);
  combine_k<<<dim3(8, 64), dim3(256), 0, stream>>>(
      Xpart, Xpart + 64ull * 65536, b_bn, P0, mu, nrm_part);

  const dim3 cg(256), cb(512);
  // cov: Z0 = 1.5I - 0.5*An -> P2   (X = P0)
  col_k<0><<<cg, cb, 0, stream>>>(P0, P0, nullptr, nullptr, nullptr, P2, mu, nrm_part, nullptr);
  // Y0 = 3*Z0 - 2*Z0^2 -> P3
  col_k<1><<<cg, cb, 0, stream>>>(P2, P2, nullptr, nullptr, P3, nullptr, nullptr, nullptr, nullptr);
  // it1: Z=P2, Y=P3 -> Yn P0, Zn P1
  col_k<2><<<cg, cb, 0, stream>>>(P2, P3, P3, P2, P0, P1, nullptr, nullptr, nullptr);
  // it2: Z=P1, Y=P0 -> Yn P3, Zn P2
  col_k<2><<<cg, cb, 0, stream>>>(P1, P0, P0, P1, P3, P2, nullptr, nullptr, nullptr);
  // it3: Z=P2, Y=P3 -> Yn P1, Zn P0
  col_k<2><<<cg, cb, 0, stream>>>(P2, P3, P3, P2, P1, P0, nullptr, nullptr, nullptr);
  // fin: Z=P0, Y=P1 -> Sf (permuted-linear)
  col_k<3><<<cg, cb, 0, stream>>>(P0, P1, P1, nullptr, nullptr, nullptr, nullptr, nrm_part, Sf);

  head2<<<dim3(64, 5), dim3(256), 0, stream>>>(Sf, W2, b_type, b_flag, out);
  (void)in_sizes; (void)n_in; (void)out_size; (void)ws_size;
}